// Round 4
// baseline (623.934 us; speedup 1.0000x reference)
//
#include <hip/hip_runtime.h>

constexpr int TAGS = 64;
constexpr int START_T = 62;
constexpr int END_T = 63;
constexpr float NEGF = -10000.0f;
constexpr int L_DIM = 512;
constexpr int B_DIM = 1024;

typedef float v2f __attribute__((ext_vector_type(2)));
typedef float v4f __attribute__((ext_vector_type(4)));

__device__ __forceinline__ float lane_bcast(float x, int lane) {
    return __int_as_float(__builtin_amdgcn_readlane(__float_as_int(x), lane));
}

__device__ __forceinline__ float wave_max64(float x) {
#pragma unroll
    for (int off = 32; off >= 1; off >>= 1)
        x = fmaxf(x, __shfl_xor(x, off, 64));
    return x;
}

__device__ __forceinline__ float wave_sum64(float x) {
#pragma unroll
    for (int off = 32; off >= 1; off >>= 1)
        x += __shfl_xor(x, off, 64);
    return x;
}

// Packed fp32 FMA (2 fp32 per instr). acc = e*v + acc, in place.
__device__ __forceinline__ void pk_fma(v2f& acc, v2f e, v2f v) {
    asm volatile("v_pk_fma_f32 %0, %1, %2, %0" : "+v"(acc) : "v"(e), "v"(v));
}

// One wave per block, one batch item per wave. lane = destination tag.
// Scan step: new[i] = feat[i] + M + log( sum_j E[i,j]*exp(alpha[j]-M) ),
// E = exp(transition) held in VGPRs as 32 float2 pairs; v broadcast via LDS
// (uniform-address ds_read_b128 = hw broadcast, no bank conflicts).
// M is a running wave-uniform offset (alpha[0]); any uniform M cancels
// exactly, only over/underflow matters (finite alphas span << exp range).
//
// R3 LESSON: the LDS broadcast MUST have an lgkmcnt drain between the
// ds_write and the cross-lane ds_reads (R3 raced: post-timing absmax 96,
// one-iter-stale v values). __syncthreads() per step (cheap for a 1-wave
// block: s_waitcnt lgkmcnt(0)+s_barrier) fixes RAW; double-buffered vbuf
// fixes WAR across the single barrier.
__global__ __attribute__((amdgpu_waves_per_eu(1))) __launch_bounds__(64)
void crf_fused(
    const float* __restrict__ feats,
    const int* __restrict__ tags,
    const float* __restrict__ mask,
    const float* __restrict__ trans,
    float* __restrict__ out)
{
    __shared__ float sE[TAGS][TAGS + 2];             // +2 keeps v2f rows 8B-aligned
    __shared__ __align__(16) float vbuf[2][TAGS];    // double buffer: WAR safety
    const int lane = threadIdx.x;                    // t_new
    const int b    = blockIdx.x;                     // batch item

    // Stage E = exp(transition) (one-time; precise expf for the table).
#pragma unroll
    for (int k = 0; k < TAGS; ++k)
        sE[k][lane] = expf(trans[k * TAGS + lane]);  // exp(-10000) -> 0 exactly
    __syncthreads();

    // Each lane's E row as 32 register pairs (64 VGPRs). waves_per_eu(1)
    // gives a 512-VGPR budget so the allocator has no occupancy motive to
    // shuffle these through AGPRs (R2: VGPR=44 => it did). Keep-alive asm
    // prevents re-materialization as per-step LDS reads (R1: VGPR=48).
    v2f Erow[TAGS / 2];
#pragma unroll
    for (int j = 0; j < TAGS / 2; ++j)
        Erow[j] = *(const v2f*)&sE[lane][2 * j];
#pragma unroll
    for (int j = 0; j < TAGS / 2; ++j) asm volatile("" : "+v"(Erow[j]));

    float a = (lane == START_T) ? 0.0f : NEGF;       // alpha0
    float M = 0.0f;                                  // true max of alpha0

    const float* fptr = feats + (size_t)b * TAGS + lane;
    const size_t fstride = (size_t)B_DIM * TAGS;
    const float* mptr = mask + b;

    float f0 = fptr[0];
    float f1 = fptr[fstride];
    float m0 = mptr[0];
    float m1 = mptr[B_DIM];

#pragma unroll 1
    for (int l = 0; l < L_DIM; ++l) {
        // 2-deep prefetch (independent of the loop-carried chain).
        float f2 = (l + 2 < L_DIM) ? fptr[(size_t)(l + 2) * fstride] : 0.0f;
        float m2 = (l + 2 < L_DIM) ? mptr[(size_t)(l + 2) * B_DIM] : 0.0f;

        float v = __expf(a - M);                     // underflow->0 ok (incl. START)
        float* vb = vbuf[l & 1];
        vb[lane] = v;
        __syncthreads();   // drain ds_write before cross-lane reads (R3 race fix)

        v2f acc0 = {0.f, 0.f}, acc1 = {0.f, 0.f};
        v2f acc2 = {0.f, 0.f}, acc3 = {0.f, 0.f};
#pragma unroll
        for (int k = 0; k < TAGS / 4; ++k) {         // 16x uniform b128 broadcasts
            v4f vv = *(const v4f*)&vb[4 * k];
            if (k & 1) {
                pk_fma(acc2, Erow[2 * k],     vv.lo);
                pk_fma(acc3, Erow[2 * k + 1], vv.hi);
            } else {
                pk_fma(acc0, Erow[2 * k],     vv.lo);
                pk_fma(acc1, Erow[2 * k + 1], vv.hi);
            }
        }
        v2f t = (acc0 + acc1) + (acc2 + acc3);
        float ssum = t.x + t.y;

        float na = f0 + M + __logf(ssum);            // log(0) = -inf for t_new=START
        na = fmaxf(na, -1e30f);                      // keep finite: -inf*0 would NaN
        a = na * m0 + a * (1.0f - m0);               // exact when m is 0 or 1

        M = lane_bcast(a, 0);                        // running offset, 1 instr

        f0 = f1; f1 = f2;
        m0 = m1; m1 = m2;
    }

    // allpath = LSE_i(alpha[i] + trans[END,i])  (one-time: exact max fine)
    float x = a + trans[END_T * TAGS + lane];
    float Mx = wave_max64(x);
    float ex = __expf(x - Mx);
    float S = wave_sum64(ex);
    float allp = Mx + __logf(S);

    // realpath: lanes split L (8 steps each), then wave-reduce.
    float sc = 0.0f, lensum = 0.0f;
#pragma unroll
    for (int k = 0; k < L_DIM / 64; ++k) {
        int l = lane + 64 * k;
        int tg = tags[l * B_DIM + b];
        int pv = (l == 0) ? START_T : tags[(l - 1) * B_DIM + b];
        float m = mask[l * B_DIM + b];
        float emit = feats[((size_t)l * B_DIM + b) * TAGS + tg];
        float tr = trans[tg * TAGS + pv];
        sc += (emit + tr) * m;
        lensum += m;
    }
    sc = wave_sum64(sc);
    lensum = wave_sum64(lensum);
    int len = (int)lensum;                           // mask sum exact in fp32
    int last_tag = (len == 0) ? START_T : tags[(len - 1) * B_DIM + b];
    float realp = sc + trans[END_T * TAGS + last_tag];

    if (lane == 0) out[b] = allp - realp;
}

extern "C" void kernel_launch(void* const* d_in, const int* in_sizes, int n_in,
                              void* d_out, int out_size, void* d_ws, size_t ws_size,
                              hipStream_t stream) {
    const float* feats = (const float*)d_in[0];
    const int*   tags  = (const int*)d_in[1];
    const float* mask  = (const float*)d_in[2];
    const float* trans = (const float*)d_in[3];
    float* out = (float*)d_out;

    dim3 block(64, 1, 1);          // 1 wave per block
    dim3 grid(B_DIM, 1, 1);        // 1024 waves = 1 per SIMD across 256 CUs
    hipLaunchKernelGGL(crf_fused, grid, block, 0, stream,
                       feats, tags, mask, trans, out);
}

// Round 5
// 486.563 us; speedup vs baseline: 1.2823x; 1.2823x over previous
//
#include <hip/hip_runtime.h>

constexpr int TAGS = 64;
constexpr int START_T = 62;
constexpr int END_T = 63;
constexpr float NEGF = -10000.0f;
constexpr int L_DIM = 512;
constexpr int B_DIM = 1024;

typedef float v2f __attribute__((ext_vector_type(2)));
typedef float v4f __attribute__((ext_vector_type(4)));

__device__ __forceinline__ float lane_bcast(float x, int lane) {
    return __int_as_float(__builtin_amdgcn_readlane(__float_as_int(x), lane));
}

__device__ __forceinline__ float wave_max64(float x) {
#pragma unroll
    for (int off = 32; off >= 1; off >>= 1)
        x = fmaxf(x, __shfl_xor(x, off, 64));
    return x;
}

__device__ __forceinline__ float wave_sum64(float x) {
#pragma unroll
    for (int off = 32; off >= 1; off >>= 1)
        x += __shfl_xor(x, off, 64);
    return x;
}

// One wave per block, one batch item per wave. lane = destination tag.
// Scan step: new[i] = feat[i] + M + log( sum_j E[i,j]*exp(alpha[j]-M) ),
// E = exp(transition) register-resident; v broadcast via LDS
// (uniform-address ds_read_b128 = hw broadcast, no bank conflicts).
// M = running wave-uniform offset (alpha[0]); any uniform M cancels exactly.
//
// SYNC HISTORY (do not regress):
//  R3: ds_write -> ds_read with NO fence raced (post-timing absmax 96).
//  R4: __syncthreads() fixed it but emits s_waitcnt vmcnt(0) -> drained the
//      global prefetch queue every step, exposing HBM latency (490us, VALU 13%).
//  R5: minimal fence = asm s_waitcnt lgkmcnt(0) (+sched_barrier, rule #18).
//      LDS pipe drained, global loads stay in flight. WAR covered by vbuf[2].
__global__ __attribute__((amdgpu_waves_per_eu(1))) __launch_bounds__(64)
void crf_fused(
    const float* __restrict__ feats,
    const int* __restrict__ tags,
    const float* __restrict__ mask,
    const float* __restrict__ trans,
    float* __restrict__ out)
{
    __shared__ float sE[TAGS][TAGS + 2];             // +2: keeps v2f rows aligned, 2-way-max banks (free)
    __shared__ __align__(16) float vbuf[2][TAGS];    // double buffer: WAR safety
    const int lane = threadIdx.x;                    // t_new
    const int b    = blockIdx.x;                     // batch item

    // Stage E = exp(transition) (one-time; precise expf for the table).
#pragma unroll
    for (int k = 0; k < TAGS; ++k)
        sE[k][lane] = expf(trans[k * TAGS + lane]);  // exp(-10000) -> 0 exactly
    __syncthreads();

    // Each lane's E row as 32 float2 pairs. Keep-alive asm prevents per-step
    // re-materialization from LDS (R1: compiler sank 64 ds_reads into the loop).
    v2f Erow[TAGS / 2];
#pragma unroll
    for (int j = 0; j < TAGS / 2; ++j)
        Erow[j] = *(const v2f*)&sE[lane][2 * j];
#pragma unroll
    for (int j = 0; j < TAGS / 2; ++j) asm volatile("" : "+v"(Erow[j]));

    float a = (lane == START_T) ? 0.0f : NEGF;       // alpha0
    float M = 0.0f;                                  // true max of alpha0

    const float* fptr = feats + (size_t)b * TAGS + lane;
    const size_t fstride = (size_t)B_DIM * TAGS;
    const float* mptr = mask + b;

    // 4-deep prefetch: step chain ~250cy, HBM miss ~900cy -> need >=4 in flight.
    float f0 = fptr[0];
    float f1 = fptr[fstride];
    float f2 = fptr[2 * fstride];
    float f3 = fptr[3 * fstride];
    float m0 = mptr[0];
    float m1 = mptr[B_DIM];
    float m2 = mptr[2 * B_DIM];
    float m3 = mptr[3 * B_DIM];

#pragma unroll 4
    for (int l = 0; l < L_DIM; ++l) {
        float f4 = (l + 4 < L_DIM) ? fptr[(size_t)(l + 4) * fstride] : 0.0f;
        float m4 = (l + 4 < L_DIM) ? mptr[(size_t)(l + 4) * B_DIM] : 0.0f;

        float v = __expf(a - M);                     // underflow->0 ok (incl. START)
        float* vb = vbuf[l & 1];
        vb[lane] = v;
        // Minimal RAW fence: drain LDS only (NOT vmcnt -> prefetch stays in flight).
        asm volatile("s_waitcnt lgkmcnt(0)" ::: "memory");
        __builtin_amdgcn_sched_barrier(0);

        v2f acc0 = {0.f, 0.f}, acc1 = {0.f, 0.f};
        v2f acc2 = {0.f, 0.f}, acc3 = {0.f, 0.f};
#pragma unroll
        for (int k = 0; k < TAGS / 4; ++k) {         // 16x uniform b128 broadcasts
            v4f vv = *(const v4f*)&vb[4 * k];
            v2f lo = {vv.x, vv.y};
            v2f hi = {vv.z, vv.w};
            if (k & 1) {
                acc2 = __builtin_elementwise_fma(Erow[2 * k],     lo, acc2);
                acc3 = __builtin_elementwise_fma(Erow[2 * k + 1], hi, acc3);
            } else {
                acc0 = __builtin_elementwise_fma(Erow[2 * k],     lo, acc0);
                acc1 = __builtin_elementwise_fma(Erow[2 * k + 1], hi, acc1);
            }
        }
        v2f t = (acc0 + acc1) + (acc2 + acc3);
        float ssum = t.x + t.y;

        float na = f0 + M + __logf(ssum);            // log(0) = -inf for t_new=START
        na = fmaxf(na, -1e30f);                      // keep finite: -inf*0 would NaN
        a = na * m0 + a * (1.0f - m0);               // exact when m is 0 or 1

        M = lane_bcast(a, 0);                        // running offset, 1 instr

        f0 = f1; f1 = f2; f2 = f3; f3 = f4;
        m0 = m1; m1 = m2; m2 = m3; m3 = m4;
    }

    // allpath = LSE_i(alpha[i] + trans[END,i])  (one-time: exact max fine)
    float x = a + trans[END_T * TAGS + lane];
    float Mx = wave_max64(x);
    float ex = __expf(x - Mx);
    float S = wave_sum64(ex);
    float allp = Mx + __logf(S);

    // realpath: lanes split L (8 steps each), then wave-reduce.
    float sc = 0.0f, lensum = 0.0f;
#pragma unroll
    for (int k = 0; k < L_DIM / 64; ++k) {
        int l = lane + 64 * k;
        int tg = tags[l * B_DIM + b];
        int pv = (l == 0) ? START_T : tags[(l - 1) * B_DIM + b];
        float m = mask[l * B_DIM + b];
        float emit = feats[((size_t)l * B_DIM + b) * TAGS + tg];
        float tr = trans[tg * TAGS + pv];
        sc += (emit + tr) * m;
        lensum += m;
    }
    sc = wave_sum64(sc);
    lensum = wave_sum64(lensum);
    int len = (int)lensum;                           // mask sum exact in fp32
    int last_tag = (len == 0) ? START_T : tags[(len - 1) * B_DIM + b];
    float realp = sc + trans[END_T * TAGS + last_tag];

    if (lane == 0) out[b] = allp - realp;
}

extern "C" void kernel_launch(void* const* d_in, const int* in_sizes, int n_in,
                              void* d_out, int out_size, void* d_ws, size_t ws_size,
                              hipStream_t stream) {
    const float* feats = (const float*)d_in[0];
    const int*   tags  = (const int*)d_in[1];
    const float* mask  = (const float*)d_in[2];
    const float* trans = (const float*)d_in[3];
    float* out = (float*)d_out;

    dim3 block(64, 1, 1);          // 1 wave per block
    dim3 grid(B_DIM, 1, 1);        // 1024 waves = 1 per SIMD across 256 CUs
    hipLaunchKernelGGL(crf_fused, grid, block, 0, stream,
                       feats, tags, mask, trans, out);
}

// Round 6
// 358.461 us; speedup vs baseline: 1.7406x; 1.3574x over previous
//
#include <hip/hip_runtime.h>

constexpr int TAGS = 64;
constexpr int START_T = 62;
constexpr int END_T = 63;
constexpr float NEGF = -10000.0f;
constexpr int L_DIM = 512;
constexpr int B_DIM = 1024;

typedef float v2f __attribute__((ext_vector_type(2)));
typedef float v4f __attribute__((ext_vector_type(4)));

__device__ __forceinline__ float lane_bcast(float x, int lane) {
    return __int_as_float(__builtin_amdgcn_readlane(__float_as_int(x), lane));
}

__device__ __forceinline__ float wave_max64(float x) {
#pragma unroll
    for (int off = 32; off >= 1; off >>= 1)
        x = fmaxf(x, __shfl_xor(x, off, 64));
    return x;
}

__device__ __forceinline__ float wave_sum64(float x) {
#pragma unroll
    for (int off = 32; off >= 1; off >>= 1)
        x += __shfl_xor(x, off, 64);
    return x;
}

// One wave per block, one batch item per wave. lane = destination tag.
// Scan step: new[i] = feat[i] + M + log( sum_j E[i,j]*exp(alpha[j]-M) ),
// E = exp(transition) register-resident; v broadcast via LDS
// (uniform-address ds_read_b128 = hw broadcast, conflict-free).
// M = running wave-uniform offset (alpha[0]); any uniform M cancels exactly.
//
// SYNC HISTORY (do not regress):
//  R3: ds_write -> ds_read, NO fence: raced (post-timing absmax 96).
//  R4: __syncthreads(): correct but emits s_waitcnt vmcnt(0) -> drained the
//      feats prefetch every step (490us, VALU 13%).
//  R5: asm lgkmcnt(0): still 365us. Diagnosis: the wave-uniform __restrict__
//      mask load was scalarized to s_load (SMEM counts in lgkmcnt!) -> the
//      fence waited ~900cy cold-HBM scalar loads every step.
//  R6: mask lives in 8 per-lane VGPRs (one-time load), broadcast per step
//      via v_readlane (dynamic SGPR lane index, zero memory ops). The fence
//      now drains ONLY the 4-byte ds_write. feats stay lane-strided
//      global_loads (vmcnt-only), 4-deep prefetch, untouched by the fence.
__global__ __attribute__((amdgpu_waves_per_eu(1))) __launch_bounds__(64)
void crf_fused(
    const float* __restrict__ feats,
    const int* __restrict__ tags,
    const float* __restrict__ mask,
    const float* __restrict__ trans,
    float* __restrict__ out)
{
    __shared__ float sE[TAGS][TAGS + 2];             // +2 keeps v2f rows aligned
    __shared__ __align__(16) float vbuf[2][TAGS];    // double buffer: WAR safety
    const int lane = threadIdx.x;                    // t_new
    const int b    = blockIdx.x;                     // batch item

    // Stage E = exp(transition) (one-time; precise expf for the table).
#pragma unroll
    for (int k = 0; k < TAGS; ++k)
        sE[k][lane] = expf(trans[k * TAGS + lane]);  // exp(-10000) -> 0 exactly
    __syncthreads();

    // Each lane's E row as 32 float2 pairs. Keep-alive asm prevents per-step
    // re-materialization from LDS (R1: compiler sank 64 ds_reads into loop).
    v2f Erow[TAGS / 2];
#pragma unroll
    for (int j = 0; j < TAGS / 2; ++j)
        Erow[j] = *(const v2f*)&sE[lane][2 * j];
#pragma unroll
    for (int j = 0; j < TAGS / 2; ++j) asm volatile("" : "+v"(Erow[j]));

    // Mask -> registers: lane holds mask[64k+lane] in mreg[k]. One-time,
    // uncoalesced but tiny (512 dwords/wave). Kills all SMEM in the loop.
    float mreg[L_DIM / 64];
#pragma unroll
    for (int k = 0; k < L_DIM / 64; ++k)
        mreg[k] = mask[(size_t)(64 * k + lane) * B_DIM + b];

    float a = (lane == START_T) ? 0.0f : NEGF;       // alpha0
    float M = 0.0f;                                  // true max of alpha0

    const float* fptr = feats + (size_t)b * TAGS + lane;
    const size_t fstride = (size_t)B_DIM * TAGS;

    // 4-deep feats prefetch (vector global_loads, vmcnt-only).
    float f0 = fptr[0];
    float f1 = fptr[fstride];
    float f2 = fptr[2 * fstride];
    float f3 = fptr[3 * fstride];

#pragma unroll 1
    for (int k = 0; k < L_DIM / 64; ++k) {
        float mk = mreg[k];          // once per 64 steps; off the critical path
#pragma unroll 4
        for (int j = 0; j < 64; ++j) {
            const int l = (k << 6) + j;
            float f4 = (l + 4 < L_DIM) ? fptr[(size_t)(l + 4) * fstride] : 0.0f;
            float m0 = lane_bcast(mk, j);            // mask[l][b], zero-latency

            float v = __expf(a - M);                 // underflow->0 ok (incl. START)
            float* vb = vbuf[l & 1];
            vb[lane] = v;
            // Minimal RAW fence: with mask in regs and feats on vmcnt, the
            // ONLY outstanding lgkm op here is our 4-byte ds_write.
            asm volatile("s_waitcnt lgkmcnt(0)" ::: "memory");
            __builtin_amdgcn_sched_barrier(0);

            v2f acc0 = {0.f, 0.f}, acc1 = {0.f, 0.f};
            v2f acc2 = {0.f, 0.f}, acc3 = {0.f, 0.f};
#pragma unroll
            for (int t = 0; t < TAGS / 4; ++t) {     // 16x uniform b128 broadcasts
                v4f vv = *(const v4f*)&vb[4 * t];
                v2f lo = {vv.x, vv.y};
                v2f hi = {vv.z, vv.w};
                if (t & 1) {
                    acc2 = __builtin_elementwise_fma(Erow[2 * t],     lo, acc2);
                    acc3 = __builtin_elementwise_fma(Erow[2 * t + 1], hi, acc3);
                } else {
                    acc0 = __builtin_elementwise_fma(Erow[2 * t],     lo, acc0);
                    acc1 = __builtin_elementwise_fma(Erow[2 * t + 1], hi, acc1);
                }
            }
            v2f tt = (acc0 + acc1) + (acc2 + acc3);
            float ssum = tt.x + tt.y;

            float na = f0 + M + __logf(ssum);        // log(0) = -inf for START
            na = fmaxf(na, -1e30f);                  // keep finite: -inf*0 = NaN
            a = na * m0 + a * (1.0f - m0);           // exact when m is 0 or 1

            M = lane_bcast(a, 0);                    // running offset, 1 instr

            f0 = f1; f1 = f2; f2 = f3; f3 = f4;
        }
    }

    // allpath = LSE_i(alpha[i] + trans[END,i])  (one-time: exact max fine)
    float x = a + trans[END_T * TAGS + lane];
    float Mx = wave_max64(x);
    float ex = __expf(x - Mx);
    float S = wave_sum64(ex);
    float allp = Mx + __logf(S);

    // realpath: lanes split L (8 steps each), then wave-reduce.
    // mask for step lane+64k is exactly mreg[k] (same layout) — no reload.
    float sc = 0.0f, lensum = 0.0f;
#pragma unroll
    for (int k = 0; k < L_DIM / 64; ++k) {
        int l = lane + 64 * k;
        int tg = tags[l * B_DIM + b];
        int pv = (l == 0) ? START_T : tags[(l - 1) * B_DIM + b];
        float m = mreg[k];
        float emit = feats[((size_t)l * B_DIM + b) * TAGS + tg];
        float tr = trans[tg * TAGS + pv];
        sc += (emit + tr) * m;
        lensum += m;
    }
    sc = wave_sum64(sc);
    lensum = wave_sum64(lensum);
    int len = (int)lensum;                           // mask sum exact in fp32
    int last_tag = (len == 0) ? START_T : tags[(len - 1) * B_DIM + b];
    float realp = sc + trans[END_T * TAGS + last_tag];

    if (lane == 0) out[b] = allp - realp;
}

extern "C" void kernel_launch(void* const* d_in, const int* in_sizes, int n_in,
                              void* d_out, int out_size, void* d_ws, size_t ws_size,
                              hipStream_t stream) {
    const float* feats = (const float*)d_in[0];
    const int*   tags  = (const int*)d_in[1];
    const float* mask  = (const float*)d_in[2];
    const float* trans = (const float*)d_in[3];
    float* out = (float*)d_out;

    dim3 block(64, 1, 1);          // 1 wave per block
    dim3 grid(B_DIM, 1, 1);        // 1024 waves = 1 per SIMD across 256 CUs
    hipLaunchKernelGGL(crf_fused, grid, block, 0, stream,
                       feats, tags, mask, trans, out);
}